// Round 1
// baseline (469.249 us; speedup 1.0000x reference)
//
#include <hip/hip_runtime.h>
#include <hip/hip_bf16.h>
#include <cstdint>
#include <cstddef>

// MultiHeadSelfAttention: B=2, S=2048, D=1024, H=16, HD=64
// Pipeline: [QKV proj bf16-MFMA GEMM x3] -> [flash attention bf16-MFMA] -> [O proj GEMM]
// fp32->bf16 conversion fused into GEMM LDS staging (no separate convert pass).

#define B_  2
#define S_  2048
#define D_  1024
#define H_  16
#define HD_ 64

typedef __bf16 bf16x8 __attribute__((ext_vector_type(8)));
typedef float  f32x4  __attribute__((ext_vector_type(4)));

// Load 8 consecutive elements as bf16x8 (converting if fp32).
__device__ __forceinline__ bf16x8 ld8(const float* p) {
  const float4 a = *(const float4*)p;
  const float4 b = *(const float4*)(p + 4);
  bf16x8 r;
  r[0] = (__bf16)a.x; r[1] = (__bf16)a.y; r[2] = (__bf16)a.z; r[3] = (__bf16)a.w;
  r[4] = (__bf16)b.x; r[5] = (__bf16)b.y; r[6] = (__bf16)b.z; r[7] = (__bf16)b.w;
  return r;
}
__device__ __forceinline__ bf16x8 ld8(const __bf16* p) {
  return *(const bf16x8*)p;
}

// C[M][N] = A[M][K] * B[N][K]^T  (both K-contiguous), bf16 MFMA 16x16x32.
// 128x128 tile, BK=64, 4 waves in 2x2, each wave owns a 64x64 quadrant (4x4 acc tiles).
// LDS rows padded to 72 bf16 (144 B = 9*16 B: keeps 16B-aligned b128 reads, breaks
// the 128B-row bank aliasing -> ~2-way max, free per m136).
template<typename TA, typename TB, typename TC>
__global__ __launch_bounds__(256) void gemm_bt(const TA* __restrict__ A,
                                               const TB* __restrict__ Bm,
                                               TC* __restrict__ C,
                                               int M, int N, int K) {
  constexpr int LDT = 72;
  __shared__ __align__(16) __bf16 As[128 * LDT];
  __shared__ __align__(16) __bf16 Bs[128 * LDT];

  const int tid  = threadIdx.x;
  const int lane = tid & 63;
  const int wave = tid >> 6;
  const int l15  = lane & 15;
  const int quad = lane >> 4;
  const int wr   = wave >> 1;   // wave row within 2x2
  const int wc   = wave & 1;    // wave col
  const int m0   = blockIdx.y * 128;
  const int n0   = blockIdx.x * 128;

  const int srow = tid >> 3;        // staging row 0..31 (4 iters -> 128 rows)
  const int scol = (tid & 7) * 8;   // staging col 0..56 step 8

  f32x4 acc[4][4] = {};

  for (int k0 = 0; k0 < K; k0 += 64) {
    // ---- stage A,B tiles (fp32->bf16 cvt fused) ----
    for (int i = 0; i < 4; ++i) {
      const int row = i * 32 + srow;
      bf16x8 av = ld8(A  + (size_t)(m0 + row) * K + k0 + scol);
      bf16x8 bv = ld8(Bm + (size_t)(n0 + row) * K + k0 + scol);
      *(bf16x8*)(As + row * LDT + scol) = av;
      *(bf16x8*)(Bs + row * LDT + scol) = bv;
    }
    __syncthreads();
    // ---- 2 k-steps of 32 ----
    for (int kk = 0; kk < 2; ++kk) {
      bf16x8 af[4], bfr[4];
      for (int rt = 0; rt < 4; ++rt)
        af[rt] = *(const bf16x8*)(As + (wr * 64 + rt * 16 + l15) * LDT + kk * 32 + quad * 8);
      for (int ct = 0; ct < 4; ++ct)
        bfr[ct] = *(const bf16x8*)(Bs + (wc * 64 + ct * 16 + l15) * LDT + kk * 32 + quad * 8);
      for (int rt = 0; rt < 4; ++rt)
        for (int ct = 0; ct < 4; ++ct)
          acc[rt][ct] = __builtin_amdgcn_mfma_f32_16x16x32_bf16(af[rt], bfr[ct], acc[rt][ct], 0, 0, 0);
    }
    __syncthreads();
  }

  // ---- epilogue: C/D layout col=lane&15, row=quad*4+r ----
  for (int rt = 0; rt < 4; ++rt)
    for (int ct = 0; ct < 4; ++ct)
      for (int r = 0; r < 4; ++r) {
        const int row = m0 + wr * 64 + rt * 16 + quad * 4 + r;
        const int col = n0 + wc * 64 + ct * 16 + l15;
        C[(size_t)row * N + col] = (TC)acc[rt][ct][r];
      }
}

// Flash attention. Q,K,V,ctx stored as [B*S][D] bf16, head h occupies cols h*64..h*64+63.
// One workgroup per (b, h, 64 q-rows); 4 waves, each owns 16 q-rows.
// Q/K frags load straight from global (16B contiguous). V transposed into LDS.
// P (C-layout) -> LDS -> A-layout reload for PV (m120-verified transform).
__global__ __launch_bounds__(256) void attn_kernel(const __bf16* __restrict__ Q,
                                                   const __bf16* __restrict__ K,
                                                   const __bf16* __restrict__ V,
                                                   const float* __restrict__ mask,
                                                   __bf16* __restrict__ O) {
  constexpr int LDT = 72;
  __shared__ __align__(16) __bf16 vt[64 * LDT];      // [hd][key]
  __shared__ __align__(16) __bf16 ps[4][16 * LDT];   // per-wave P scratch [row][key]

  const int tid  = threadIdx.x;
  const int lane = tid & 63;
  const int wave = tid >> 6;
  const int l15  = lane & 15;
  const int quad = lane >> 4;
  const int b    = blockIdx.z;
  const int h    = blockIdx.y;
  const int q0   = blockIdx.x * 64;
  const size_t base = (size_t)b * S_ * D_ + (size_t)h * HD_;  // row-0, this head's col-0

  // Q fragments for this wave's 16 rows (k=64 -> two 32-k blocks)
  bf16x8 qf[2];
  {
    const __bf16* qp = Q + base + (size_t)(q0 + wave * 16 + l15) * D_ + quad * 8;
    qf[0] = *(const bf16x8*)(qp);
    qf[1] = *(const bf16x8*)(qp + 32);
  }

  float m_run[4], l_run[4];
  f32x4 oacc[4] = {};
  for (int r = 0; r < 4; ++r) { m_run[r] = -1e30f; l_run[r] = 0.f; }

  for (int t0 = 0; t0 < S_; t0 += 64) {
    __syncthreads();  // protect vt from previous iteration's readers
    // ---- stage V tile transposed: vt[hd][key], coalesced global reads ----
    for (int i = 0; i < 8; ++i) {
      const int e   = i * 256 + tid;     // 0..2047 (pairs of bf16)
      const int key = e >> 5;            // 0..63
      const int hd2 = (e & 31) * 2;      // 0..62
      const __bf16* vp = V + base + (size_t)(t0 + key) * D_ + hd2;
      const __bf16 v0 = vp[0], v1 = vp[1];
      vt[hd2 * LDT + key]       = v0;
      vt[(hd2 + 1) * LDT + key] = v1;
    }
    __syncthreads();

    // ---- scores: S = Q * K^T (16 q-rows x 64 keys per wave) ----
    f32x4 sacc[4] = {};
    for (int nt = 0; nt < 4; ++nt) {
      const __bf16* kp = K + base + (size_t)(t0 + nt * 16 + l15) * D_ + quad * 8;
      bf16x8 kf0 = *(const bf16x8*)(kp);
      bf16x8 kf1 = *(const bf16x8*)(kp + 32);
      sacc[nt] = __builtin_amdgcn_mfma_f32_16x16x32_bf16(qf[0], kf0, sacc[nt], 0, 0, 0);
      sacc[nt] = __builtin_amdgcn_mfma_f32_16x16x32_bf16(qf[1], kf1, sacc[nt], 0, 0, 0);
    }

    // scale + additive mask (mask is [B,1,1,S] -> per-key)
    float s[4][4];  // [nt][r]
    for (int nt = 0; nt < 4; ++nt) {
      const float mv = mask[(size_t)b * S_ + t0 + nt * 16 + l15];
      for (int r = 0; r < 4; ++r) s[nt][r] = sacc[nt][r] * 0.125f + mv;
    }

    // ---- online softmax (row = quad*4+r; reduce across the 16 lanes of the quad) ----
    float mnew[4], alpha[4];
    for (int r = 0; r < 4; ++r) {
      float tm = fmaxf(fmaxf(s[0][r], s[1][r]), fmaxf(s[2][r], s[3][r]));
      for (int off = 1; off < 16; off <<= 1) tm = fmaxf(tm, __shfl_xor(tm, off));
      mnew[r]  = fmaxf(m_run[r], tm);
      alpha[r] = __expf(m_run[r] - mnew[r]);
      m_run[r] = mnew[r];
    }
    float tsum[4] = {0.f, 0.f, 0.f, 0.f};
    for (int nt = 0; nt < 4; ++nt)
      for (int r = 0; r < 4; ++r) {
        const float p = __expf(s[nt][r] - mnew[r]);
        tsum[r] += p;
        ps[wave][(quad * 4 + r) * LDT + nt * 16 + l15] = (__bf16)p;
      }
    for (int r = 0; r < 4; ++r) {
      float ts = tsum[r];
      for (int off = 1; off < 16; off <<= 1) ts += __shfl_xor(ts, off);
      l_run[r] = l_run[r] * alpha[r] + ts;
    }
    for (int nt = 0; nt < 4; ++nt)
      for (int r = 0; r < 4; ++r) oacc[nt][r] *= alpha[r];

    __syncthreads();  // P writes visible before A-layout reload

    // ---- O += P * V ----
    for (int kb = 0; kb < 2; ++kb) {
      bf16x8 pf = *(const bf16x8*)(&ps[wave][l15 * LDT + kb * 32 + quad * 8]);
      for (int nt = 0; nt < 4; ++nt) {
        bf16x8 vf = *(const bf16x8*)(&vt[(nt * 16 + l15) * LDT + kb * 32 + quad * 8]);
        oacc[nt] = __builtin_amdgcn_mfma_f32_16x16x32_bf16(pf, vf, oacc[nt], 0, 0, 0);
      }
    }
  }

  // ---- epilogue: ctx = O / l ----
  for (int nt = 0; nt < 4; ++nt)
    for (int r = 0; r < 4; ++r) {
      const int row = q0 + wave * 16 + quad * 4 + r;
      const int col = nt * 16 + l15;
      O[base + (size_t)row * D_ + col] = (__bf16)(oacc[nt][r] / l_run[r]);
    }
}

extern "C" void kernel_launch(void* const* d_in, const int* in_sizes, int n_in,
                              void* d_out, int out_size, void* d_ws, size_t ws_size,
                              hipStream_t stream) {
  const float* x    = (const float*)d_in[0];
  const float* mask = (const float*)d_in[1];
  const float* Wq   = (const float*)d_in[2];
  const float* Wk   = (const float*)d_in[3];
  const float* Wv   = (const float*)d_in[4];
  const float* Wo   = (const float*)d_in[5];
  float* out = (float*)d_out;

  char* ws = (char*)d_ws;
  const size_t SZ = (size_t)B_ * S_ * D_ * sizeof(__bf16);  // 8 MiB each
  __bf16* qb = (__bf16*)(ws);
  __bf16* kb = (__bf16*)(ws + SZ);
  __bf16* vb = (__bf16*)(ws + 2 * SZ);
  __bf16* cb = (__bf16*)(ws + 3 * SZ);

  const int M = B_ * S_;  // 4096
  dim3 blk(256);
  dim3 gg(D_ / 128, M / 128);  // (8, 32)

  gemm_bt<float, float, __bf16><<<gg, blk, 0, stream>>>(x, Wq, qb, M, D_, D_);
  gemm_bt<float, float, __bf16><<<gg, blk, 0, stream>>>(x, Wk, kb, M, D_, D_);
  gemm_bt<float, float, __bf16><<<gg, blk, 0, stream>>>(x, Wv, vb, M, D_, D_);

  dim3 ga(S_ / 64, H_, B_);  // (32, 16, 2)
  attn_kernel<<<ga, blk, 0, stream>>>(qb, kb, vb, mask, cb);

  gemm_bt<__bf16, float, float><<<gg, blk, 0, stream>>>(cb, Wo, out, M, D_, D_);
}

// Round 2
// 232.739 us; speedup vs baseline: 2.0162x; 2.0162x over previous
//
#include <hip/hip_runtime.h>
#include <hip/hip_bf16.h>
#include <cstdint>
#include <cstddef>

// MHA B=2,S=2048,D=1024,H=16,HD=64.
// cvt(fp32->bf16) -> fused QKV GEMM (m97 global_load_lds) -> V-transpose ->
// flash attn (S^T form, 128q x 128k tiles) -> O GEMM.

#define B_  2
#define S_  2048
#define D_  1024
#define H_  16
#define HD_ 64

typedef __bf16 bf16x8 __attribute__((ext_vector_type(8)));
typedef __bf16 bf16x4 __attribute__((ext_vector_type(4)));
typedef float  f32x4  __attribute__((ext_vector_type(4)));

// ---- async global->LDS, 16B per lane. LDS dest must be wave-uniform base;
// HW adds lane*16 (guide §5 m97/m104). AS(3) ptr = low 32 bits of flat addr.
__device__ __forceinline__ void async16(const __bf16* g, const __bf16* l) {
  __builtin_amdgcn_global_load_lds(
      (const __attribute__((address_space(1))) void*)(uintptr_t)g,
      (__attribute__((address_space(3))) void*)(uint32_t)(uintptr_t)l,
      16, 0, 0);
}

// ---------------- fp32 -> bf16 convert (x + 4 weights) ----------------
__global__ __launch_bounds__(256) void cvt_all(const float* __restrict__ x,
    const float* __restrict__ wq, const float* __restrict__ wk,
    const float* __restrict__ wv, const float* __restrict__ wo,
    __bf16* __restrict__ xb, __bf16* __restrict__ wqb, __bf16* __restrict__ wkb,
    __bf16* __restrict__ wvb, __bf16* __restrict__ wob) {
  const int sel = blockIdx.y;
  const float* src; __bf16* dst; int n;
  if      (sel == 0) { src = x;  dst = xb;  n = B_ * S_ * D_; }
  else if (sel == 1) { src = wq; dst = wqb; n = D_ * D_; }
  else if (sel == 2) { src = wk; dst = wkb; n = D_ * D_; }
  else if (sel == 3) { src = wv; dst = wvb; n = D_ * D_; }
  else               { src = wo; dst = wob; n = D_ * D_; }
  for (int i = blockIdx.x * 256 + threadIdx.x; i * 4 < n; i += gridDim.x * 256) {
    const float4 v = *(const float4*)(src + (size_t)i * 4);
    bf16x4 o;
    o[0] = (__bf16)v.x; o[1] = (__bf16)v.y; o[2] = (__bf16)v.z; o[3] = (__bf16)v.w;
    *(bf16x4*)(dst + (size_t)i * 4) = o;
  }
}

// ---------------- m97-style GEMM body: C[M][N] = A[M][K] * B[N][K]^T ----------------
template <typename TC>
__device__ __forceinline__ void gemm97_body(const __bf16* __restrict__ A,
                                            const __bf16* __restrict__ Bm,
                                            TC* __restrict__ C,
                                            const int m0, const int n0,
                                            const int N, const int K) {
  __shared__ __align__(16) __bf16 As[128 * 64];  // unpadded: global_load_lds order
  __shared__ __align__(16) __bf16 Bs[128 * 64];
  const int tid  = threadIdx.x, lane = tid & 63, wave = tid >> 6;
  const int l15  = lane & 15,   quad = lane >> 4;
  const int wr   = wave >> 1,   wc   = wave & 1;
  const int ebase = wave * 2048 + lane * 8;  // elem offset this lane covers (chunk 0)

  f32x4 acc[4][4] = {};
  for (int k0 = 0; k0 < K; k0 += 64) {
#pragma unroll
    for (int i = 0; i < 4; ++i) {
      const int e = ebase + i * 512;
      const int row = e >> 6, col = e & 63;
      async16(A  + (size_t)(m0 + row) * K + k0 + col, As + (wave * 4 + i) * 512);
      async16(Bm + (size_t)(n0 + row) * K + k0 + col, Bs + (wave * 4 + i) * 512);
    }
    __syncthreads();
#pragma unroll
    for (int kk = 0; kk < 2; ++kk) {
      bf16x8 af[4], bfv[4];
#pragma unroll
      for (int rt = 0; rt < 4; ++rt)
        af[rt] = *(const bf16x8*)(As + (wr * 64 + rt * 16 + l15) * 64 + kk * 32 + quad * 8);
#pragma unroll
      for (int ct = 0; ct < 4; ++ct)
        bfv[ct] = *(const bf16x8*)(Bs + (wc * 64 + ct * 16 + l15) * 64 + kk * 32 + quad * 8);
#pragma unroll
      for (int rt = 0; rt < 4; ++rt)
#pragma unroll
        for (int ct = 0; ct < 4; ++ct)
          acc[rt][ct] = __builtin_amdgcn_mfma_f32_16x16x32_bf16(af[rt], bfv[ct], acc[rt][ct], 0, 0, 0);
    }
    __syncthreads();
  }
#pragma unroll
  for (int rt = 0; rt < 4; ++rt)
#pragma unroll
    for (int ct = 0; ct < 4; ++ct)
#pragma unroll
      for (int r = 0; r < 4; ++r) {
        const int row = m0 + wr * 64 + rt * 16 + quad * 4 + r;
        const int col = n0 + wc * 64 + ct * 16 + l15;
        C[(size_t)row * N + col] = (TC)acc[rt][ct][r];
      }
}

__global__ __launch_bounds__(256) void qkv_gemm(const __bf16* __restrict__ xb,
                                                const __bf16* __restrict__ wq,
                                                const __bf16* __restrict__ wk,
                                                const __bf16* __restrict__ wv,
                                                __bf16* __restrict__ qkv) {
  const int sel = blockIdx.x >> 3;  // 0..2 -> Q,K,V
  const __bf16* Bm = (sel == 0) ? wq : (sel == 1) ? wk : wv;
  __bf16* C = qkv + (size_t)sel * ((size_t)B_ * S_ * D_);
  gemm97_body<__bf16>(xb, Bm, C, blockIdx.y * 128, (blockIdx.x & 7) * 128, D_, D_);
}

__global__ __launch_bounds__(256) void o_gemm(const __bf16* __restrict__ cb,
                                              const __bf16* __restrict__ wo,
                                              float* __restrict__ out) {
  gemm97_body<float>(cb, wo, out, blockIdx.y * 128, blockIdx.x * 128, D_, D_);
}

// ---------------- V transpose: vb[B*S][D] -> vt[(b*16+h)*64+hd][S] ----------------
__global__ __launch_bounds__(256) void vtrans(const __bf16* __restrict__ vb,
                                              __bf16* __restrict__ vt) {
  __shared__ __bf16 tbuf[64][72];
  const int tid = threadIdx.x;
  const int s0 = blockIdx.x * 64, bh = blockIdx.y;
  const int b = bh >> 4, h = bh & 15;
  const __bf16* src = vb + ((size_t)b * S_ + s0) * D_ + h * HD_;
#pragma unroll
  for (int i = 0; i < 2; ++i) {
    const int r = i * 32 + (tid >> 3), c8 = (tid & 7) * 8;
    *(bf16x8*)(&tbuf[r][c8]) = *(const bf16x8*)(src + (size_t)r * D_ + c8);
  }
  __syncthreads();
  __bf16* dst = vt + (size_t)bh * HD_ * S_ + s0;
#pragma unroll
  for (int i = 0; i < 2; ++i) {
    const int hd = i * 32 + (tid >> 3), sc = (tid & 7) * 8;
    bf16x8 v;
#pragma unroll
    for (int j = 0; j < 8; ++j) v[j] = tbuf[sc + j][hd];
    *(bf16x8*)(dst + (size_t)hd * S_ + sc) = v;
  }
}

// ---------------- flash attention, S^T form ----------------
// Block: 128 q-rows of one (b,h); 4 waves x 32 q. KV tile = 128 keys.
// S^T = K·Q^T (A=K rows from LDS, B=Q in registers) -> softmax key-reduction is
// per-lane + 2 shuffle hops. P^T (C-layout) -> ps[q][key] (2-way-conflict b64
// writes) -> A-operand for PV. V pre-transposed globally, staged as Vt[hd][key].
__global__ __launch_bounds__(256) void attn2(const __bf16* __restrict__ Q,
                                             const __bf16* __restrict__ K,
                                             const __bf16* __restrict__ Vt,
                                             const float* __restrict__ mask,
                                             __bf16* __restrict__ O) {
  constexpr int LKT = 72, LVT = 136, LPS = 136;
  __shared__ __align__(16) __bf16 kt[128 * LKT];
  __shared__ __align__(16) __bf16 vt[64 * LVT];
  __shared__ __align__(16) __bf16 ps[128 * LPS];
  __shared__ __align__(16) float  msk[128];

  const int tid  = threadIdx.x, lane = tid & 63, wave = tid >> 6;
  const int l15  = lane & 15,   quad = lane >> 4;
  const int b = blockIdx.z, h = blockIdx.y, q0 = blockIdx.x * 128;
  const size_t base   = (size_t)b * S_ * D_ + h * HD_;
  const size_t vtbase = (size_t)(b * H_ + h) * HD_ * S_;
  const int qw = q0 + wave * 32;

  // Q fragments (B-operand: lane n=l15 -> q row, k = kb*32+quad*8+j)
  bf16x8 qf[2][2];
#pragma unroll
  for (int t = 0; t < 2; ++t)
#pragma unroll
    for (int kb = 0; kb < 2; ++kb)
      qf[t][kb] = *(const bf16x8*)(Q + base + (size_t)(qw + t * 16 + l15) * D_ + kb * 32 + quad * 8);

  float m_run[2] = {-1e30f, -1e30f}, l_run[2] = {0.f, 0.f};
  f32x4 oacc[2][4] = {};

  for (int t0 = 0; t0 < S_; t0 += 128) {
    __syncthreads();  // prior iter's readers done before restage
#pragma unroll
    for (int i = 0; i < 4; ++i) {
      const int idx = i * 256 + tid;
      { const int row = idx >> 3, c8 = (idx & 7) * 8;     // kt[128][72]
        *(bf16x8*)(kt + row * LKT + c8) =
            *(const bf16x8*)(K + base + (size_t)(t0 + row) * D_ + c8); }
      { const int row = idx >> 4, c8 = (idx & 15) * 8;    // vt[64][136]
        *(bf16x8*)(vt + row * LVT + c8) =
            *(const bf16x8*)(Vt + vtbase + (size_t)row * S_ + t0 + c8); }
    }
    if (tid < 128) msk[tid] = mask[(size_t)b * S_ + t0 + tid];
    __syncthreads();

    // S^T tiles: D[m=key][n=q]
    f32x4 sacc[8][2] = {};
#pragma unroll
    for (int kti = 0; kti < 8; ++kti) {
      const __bf16* kr = kt + (kti * 16 + l15) * LKT + quad * 8;
      const bf16x8 a0 = *(const bf16x8*)(kr);
      const bf16x8 a1 = *(const bf16x8*)(kr + 32);
#pragma unroll
      for (int t = 0; t < 2; ++t) {
        sacc[kti][t] = __builtin_amdgcn_mfma_f32_16x16x32_bf16(a0, qf[t][0], sacc[kti][t], 0, 0, 0);
        sacc[kti][t] = __builtin_amdgcn_mfma_f32_16x16x32_bf16(a1, qf[t][1], sacc[kti][t], 0, 0, 0);
      }
    }
    // scale + additive mask (per-key -> per acc row; broadcast LDS read)
#pragma unroll
    for (int kti = 0; kti < 8; ++kti) {
      const f32x4 mv = *(const f32x4*)(msk + kti * 16 + quad * 4);
#pragma unroll
      for (int t = 0; t < 2; ++t)
#pragma unroll
        for (int r = 0; r < 4; ++r)
          sacc[kti][t][r] = sacc[kti][t][r] * 0.125f + mv[r];
    }
    // online softmax: per-lane over 32 keys, then quad hops (16,32)
    float mnew[2], alpha[2], tsum[2];
#pragma unroll
    for (int t = 0; t < 2; ++t) {
      float tm = -1e30f;
#pragma unroll
      for (int kti = 0; kti < 8; ++kti)
#pragma unroll
        for (int r = 0; r < 4; ++r) tm = fmaxf(tm, sacc[kti][t][r]);
      tm = fmaxf(tm, __shfl_xor(tm, 16));
      tm = fmaxf(tm, __shfl_xor(tm, 32));
      mnew[t]  = fmaxf(m_run[t], tm);
      alpha[t] = __expf(m_run[t] - mnew[t]);
      m_run[t] = mnew[t];
      tsum[t]  = 0.f;
    }
    // P = exp(S - m), write P[q][key] (4 consecutive keys -> b64, ~2-way banks)
#pragma unroll
    for (int t = 0; t < 2; ++t) {
      __bf16* pr = ps + (size_t)(wave * 32 + t * 16 + l15) * LPS + quad * 4;
#pragma unroll
      for (int kti = 0; kti < 8; ++kti) {
        bf16x4 pv;
#pragma unroll
        for (int r = 0; r < 4; ++r) {
          const float p = __expf(sacc[kti][t][r] - mnew[t]);
          tsum[t] += p;
          pv[r] = (__bf16)p;
        }
        *(bf16x4*)(pr + kti * 16) = pv;
      }
    }
#pragma unroll
    for (int t = 0; t < 2; ++t) {
      float ts = tsum[t];
      ts += __shfl_xor(ts, 16);
      ts += __shfl_xor(ts, 32);
      l_run[t] = l_run[t] * alpha[t] + ts;
      // rescale O-acc: acc rows are q=quad*4+r, alpha lives at lane l15=q
#pragma unroll
      for (int r = 0; r < 4; ++r) {
        const float aR = __shfl(alpha[t], quad * 4 + r);
#pragma unroll
        for (int nt = 0; nt < 4; ++nt) oacc[t][nt][r] *= aR;
      }
    }
    // O += P·V  (A=ps rows, B=vt rows; per-wave ps region, no barrier needed)
#pragma unroll
    for (int kb = 0; kb < 4; ++kb) {
      bf16x8 pa[2];
#pragma unroll
      for (int t = 0; t < 2; ++t)
        pa[t] = *(const bf16x8*)(ps + (size_t)(wave * 32 + t * 16 + l15) * LPS + kb * 32 + quad * 8);
#pragma unroll
      for (int nt = 0; nt < 4; ++nt) {
        const bf16x8 vf = *(const bf16x8*)(vt + (nt * 16 + l15) * LVT + kb * 32 + quad * 8);
#pragma unroll
        for (int t = 0; t < 2; ++t)
          oacc[t][nt] = __builtin_amdgcn_mfma_f32_16x16x32_bf16(pa[t], vf, oacc[t][nt], 0, 0, 0);
      }
    }
  }
  // epilogue: divide by l (broadcast per acc row), store ctx
#pragma unroll
  for (int t = 0; t < 2; ++t)
#pragma unroll
    for (int r = 0; r < 4; ++r) {
      const float lR  = __shfl(l_run[t], quad * 4 + r);
      const float inv = 1.0f / lR;
      const int row = qw + t * 16 + quad * 4 + r;
#pragma unroll
      for (int nt = 0; nt < 4; ++nt)
        O[base + (size_t)row * D_ + nt * 16 + l15] = (__bf16)(oacc[t][nt][r] * inv);
    }
}

extern "C" void kernel_launch(void* const* d_in, const int* in_sizes, int n_in,
                              void* d_out, int out_size, void* d_ws, size_t ws_size,
                              hipStream_t stream) {
  const float* x    = (const float*)d_in[0];
  const float* mask = (const float*)d_in[1];
  const float* Wq   = (const float*)d_in[2];
  const float* Wk   = (const float*)d_in[3];
  const float* Wv   = (const float*)d_in[4];
  const float* Wo   = (const float*)d_in[5];

  char* ws = (char*)d_ws;
  const size_t MB = 1ull << 20;
  const size_t NT = (size_t)B_ * S_ * D_;  // 4M elems, 8 MB bf16
  __bf16* xb  = (__bf16*)(ws);             // 8 MB; reused as vtb after qkv_gemm
  __bf16* wqb = (__bf16*)(ws + 8 * MB);
  __bf16* wkb = (__bf16*)(ws + 10 * MB);
  __bf16* wvb = (__bf16*)(ws + 12 * MB);
  __bf16* wob = (__bf16*)(ws + 14 * MB);
  __bf16* qkv = (__bf16*)(ws + 16 * MB);   // 24 MB
  __bf16* qb  = qkv;
  __bf16* kb  = qkv + NT;
  __bf16* vb  = qkv + 2 * NT;
  __bf16* vtb = xb;   // x consumed by qkv_gemm before vtrans writes (stream order)
  __bf16* cb  = vb;   // v consumed by vtrans before attn writes ctx

  cvt_all<<<dim3(1024, 5), 256, 0, stream>>>(x, Wq, Wk, Wv, Wo, xb, wqb, wkb, wvb, wob);
  qkv_gemm<<<dim3(24, 32), 256, 0, stream>>>(xb, wqb, wkb, wvb, qkv);
  vtrans<<<dim3(32, 32), 256, 0, stream>>>(vb, vtb);
  attn2<<<dim3(S_ / 128, H_, B_), 256, 0, stream>>>(qb, kb, vtb, mask, cb);
  o_gemm<<<dim3(8, 32), 256, 0, stream>>>(cb, wob, (float*)d_out);
}